// Round 4
// baseline (129.034 us; speedup 1.0000x reference)
//
#include <hip/hip_runtime.h>
#include <math.h>

#define NSLICES 4
#define HID 512
#define IN_FEAT 342
#define OUTD 311
#define BATCH 256
#define KP0 352           // layer-0 padded K (11 chunks of 32)
#define MP2 320           // layer-2 padded M
#define XROW (IN_FEAT + 1)

typedef unsigned short u16;
typedef short bf16x8 __attribute__((ext_vector_type(8)));
typedef float f32x4 __attribute__((ext_vector_type(4)));

__device__ __forceinline__ u16 f2bf_rne(float v) {
    unsigned int x = __float_as_uint(v);
    unsigned int r = (x + 0x7fffu + ((x >> 16) & 1u)) >> 16;
    return (u16)r;
}
__device__ __forceinline__ float bf2f(u16 u) {
    return __uint_as_float(((unsigned int)u) << 16);
}

// ================= combined prep =================
// One kernel, flat item space:
//  [0, C0)            : W0 chunks  (rows 4*512, 44 chunks of 8 along KP0)
//  [C0, C0+C1)        : W1 chunks  (rows 4*512, 64 chunks)
//  [.., +C2)          : W2 chunks  (rows 4*320 padded, 64 chunks)
//  [.., +CX)          : x  chunks  (256 rows, 44 chunks along KP0)
//  [.., +256)         : dcoef (one item per batch row)
#define C0 (4 * 512 * 44)
#define C1 (4 * 512 * 64)
#define C2 (4 * 320 * 64)
#define CX (256 * 44)
#define PREP_TOT (C0 + C1 + C2 + CX + 256)

union U8 { u16 u[8]; uint4 v; };

__global__ __launch_bounds__(256) void prep_all(
    const float* __restrict__ x,
    const float* __restrict__ W0, const float* __restrict__ W1, const float* __restrict__ W2,
    u16* __restrict__ whi0, u16* __restrict__ wlo0,
    u16* __restrict__ whi1, u16* __restrict__ wlo1,
    u16* __restrict__ whi2, u16* __restrict__ wlo2,
    u16* __restrict__ h0hi, u16* __restrict__ h0lo,
    float* __restrict__ dcoef)
{
    int i = blockIdx.x * 256 + threadIdx.x;
    if (i >= PREP_TOT) return;

    if (i >= C0 + C1 + C2 + CX) {           // ---- dcoef ----
        int b = i - (C0 + C1 + C2 + CX);
        float ps = 4.f * x[(size_t)b * XROW + IN_FEAT];
        float fl = floorf(ps);
        float mu = ps - fl;
        int i1 = ((int)fl) & 3;
        float mu2 = mu * mu, mu3 = mu2 * mu;
        float c0 = -0.5f * mu3 + mu2 - 0.5f * mu;
        float c1 = 1.5f * mu3 - 2.5f * mu2 + 1.0f;
        float c2 = -1.5f * mu3 + 2.0f * mu2 + 0.5f * mu;
        float c3 = 0.5f * mu3 - 0.5f * mu2;
        float d[4];
        d[(i1 + 3) & 3] = c0;
        d[i1]           = c1;
        d[(i1 + 1) & 3] = c2;
        d[(i1 + 2) & 3] = c3;
        *reinterpret_cast<float4*>(dcoef + b * 4) = make_float4(d[0], d[1], d[2], d[3]);
        return;
    }

    float src[8];
    u16* dhi; u16* dlo; size_t doff;
    if (i < C0) {                            // ---- W0 ----
        int row = i / 44, c = i - row * 44;
        int k = c * 8;
#pragma unroll
        for (int j = 0; j < 8; j++) {
            int kk = k + j;
            src[j] = (kk < IN_FEAT) ? W0[(size_t)row * IN_FEAT + kk] : 0.f;
        }
        dhi = whi0; dlo = wlo0; doff = (size_t)row * KP0 + k;
    } else if (i < C0 + C1) {                // ---- W1 ----
        int l = i - C0;
        int row = l >> 6, c = l & 63;
        int k = c * 8;
        const float* p = W1 + (size_t)row * HID + k;
#pragma unroll
        for (int j = 0; j < 8; j++) src[j] = p[j];
        dhi = whi1; dlo = wlo1; doff = (size_t)row * HID + k;
    } else if (i < C0 + C1 + C2) {           // ---- W2 (M padded to 320) ----
        int l = i - C0 - C1;
        int row = l >> 6, c = l & 63;
        int k = c * 8;
        int s = row / 320, o = row - s * 320;
        if (o < OUTD) {
            const float* p = W2 + ((size_t)s * OUTD + o) * HID + k;
#pragma unroll
            for (int j = 0; j < 8; j++) src[j] = p[j];
        } else {
#pragma unroll
            for (int j = 0; j < 8; j++) src[j] = 0.f;
        }
        dhi = whi2; dlo = wlo2; doff = (size_t)row * HID + k;
    } else {                                 // ---- x -> H0 ----
        int l = i - C0 - C1 - C2;
        int b = l / 44, c = l - b * 44;
        int k = c * 8;
#pragma unroll
        for (int j = 0; j < 8; j++) {
            int kk = k + j;
            src[j] = (kk < IN_FEAT) ? x[(size_t)b * XROW + kk] : 0.f;
        }
        dhi = h0hi; dlo = h0lo; doff = (size_t)b * KP0 + k;
    }

    U8 hi, lo;
#pragma unroll
    for (int j = 0; j < 8; j++) {
        u16 h = f2bf_rne(src[j]);
        hi.u[j] = h;
        lo.u[j] = f2bf_rne(src[j] - bf2f(h));
    }
    *reinterpret_cast<uint4*>(dhi + doff) = hi.v;
    *reinterpret_cast<uint4*>(dlo + doff) = lo.v;
}

// ================= fused layer: GEMM(4 slices) + cubic blend + bias + (ELU) =================
// out[b][o] = act( sum_s d_s(b) * ( sum_k W[s][o][k]*H[b][k] + bias[s][o] ) )
// grid (BATCH/16, Mp/64); block 256 = 4 waves stacked in o.
// W fragments direct from global (L2/L3); H tile (16 rows x KP, hi+lo) staged once in LDS.
// FINAL=0: emit bf16 hi/lo H for next layer. FINAL=1: emit fp32 to out (guard o<M).
template<int KP, int KLDS, int FINAL>
__global__ __launch_bounds__(256) void layer_fused(
    const u16* __restrict__ Whi, const u16* __restrict__ Wlo,
    const u16* __restrict__ Hhi, const u16* __restrict__ Hlo,
    const float* __restrict__ bias, const float* __restrict__ dcoef,
    int Mp, int M,
    u16* __restrict__ Ohi, u16* __restrict__ Olo, float* __restrict__ out)
{
    __shared__ __align__(16) u16 sHhi[16 * KLDS];
    __shared__ __align__(16) u16 sHlo[16 * KLDS];

    const int tid = (int)threadIdx.x;
    const int b0 = blockIdx.x * 16;
    const int o0 = blockIdx.y * 64;

    constexpr int CH = KP / 8;
    for (int idx = tid; idx < 16 * CH; idx += 256) {
        int r = idx / CH, c = idx - r * CH;
        size_t g = (size_t)(b0 + r) * KP + c * 8;
        *reinterpret_cast<uint4*>(&sHhi[r * KLDS + c * 8]) =
            *reinterpret_cast<const uint4*>(Hhi + g);
        *reinterpret_cast<uint4*>(&sHlo[r * KLDS + c * 8]) =
            *reinterpret_cast<const uint4*>(Hlo + g);
    }
    __syncthreads();

    const int lane = tid & 63;
    const int wv = tid >> 6;
    const int m = lane & 15;
    const int q = lane >> 4;
    const int b = b0 + m;

    const float4 dv = *reinterpret_cast<const float4*>(dcoef + b * 4);
    const float ds[4] = {dv.x, dv.y, dv.z, dv.w};

    const u16* hp_hi = &sHhi[m * KLDS + q * 8];
    const u16* hp_lo = &sHlo[m * KLDS + q * 8];
    const size_t wrow0 = ((size_t)(o0 + wv * 16 + m)) * KP + q * 8;
    const size_t wplane = (size_t)Mp * KP;

    f32x4 bl = {0.f, 0.f, 0.f, 0.f};
#pragma unroll
    for (int s = 0; s < 4; ++s) {
        const u16* wp_hi = Whi + wrow0 + s * wplane;
        const u16* wp_lo = Wlo + wrow0 + s * wplane;
        f32x4 a0 = {0.f, 0.f, 0.f, 0.f};
        f32x4 a1 = {0.f, 0.f, 0.f, 0.f};
        f32x4 a2 = {0.f, 0.f, 0.f, 0.f};
#pragma unroll
        for (int c = 0; c < KP / 32; ++c) {
            bf16x8 ah = *reinterpret_cast<const bf16x8*>(wp_hi + c * 32);
            bf16x8 al = *reinterpret_cast<const bf16x8*>(wp_lo + c * 32);
            bf16x8 bh = *reinterpret_cast<const bf16x8*>(hp_hi + c * 32);
            bf16x8 b_l = *reinterpret_cast<const bf16x8*>(hp_lo + c * 32);
            a0 = __builtin_amdgcn_mfma_f32_16x16x32_bf16(ah, bh, a0, 0, 0, 0);
            a1 = __builtin_amdgcn_mfma_f32_16x16x32_bf16(ah, b_l, a1, 0, 0, 0);
            a2 = __builtin_amdgcn_mfma_f32_16x16x32_bf16(al, bh, a2, 0, 0, 0);
        }
        f32x4 sum = a0 + a1 + a2;
#pragma unroll
        for (int r = 0; r < 4; ++r) bl[r] += ds[s] * sum[r];
    }

    // epilogue: blended bias, activation, store. C layout: col = b (lane&15), row = q*4+r.
    const int obase = o0 + wv * 16 + q * 4;
    if (!FINAL) {
        float4 bb0 = *reinterpret_cast<const float4*>(bias + 0 * M + obase);
        float4 bb1 = *reinterpret_cast<const float4*>(bias + 1 * M + obase);
        float4 bb2 = *reinterpret_cast<const float4*>(bias + 2 * M + obase);
        float4 bb3 = *reinterpret_cast<const float4*>(bias + 3 * M + obase);
        float v[4];
        v[0] = bl[0] + ds[0]*bb0.x + ds[1]*bb1.x + ds[2]*bb2.x + ds[3]*bb3.x;
        v[1] = bl[1] + ds[0]*bb0.y + ds[1]*bb1.y + ds[2]*bb2.y + ds[3]*bb3.y;
        v[2] = bl[2] + ds[0]*bb0.z + ds[1]*bb1.z + ds[2]*bb2.z + ds[3]*bb3.z;
        v[3] = bl[3] + ds[0]*bb0.w + ds[1]*bb1.w + ds[2]*bb2.w + ds[3]*bb3.w;
        ushort4 h4, l4;
        u16* ph = (u16*)&h4; u16* pl = (u16*)&l4;
#pragma unroll
        for (int r = 0; r < 4; ++r) {
            float e = (v[r] > 0.f) ? v[r] : expm1f(v[r]);
            u16 h = f2bf_rne(e);
            ph[r] = h;
            pl[r] = f2bf_rne(e - bf2f(h));
        }
        *reinterpret_cast<ushort4*>(Ohi + (size_t)b * M + obase) = h4;
        *reinterpret_cast<ushort4*>(Olo + (size_t)b * M + obase) = l4;
    } else {
        float* dst = out + (size_t)b * M;
#pragma unroll
        for (int r = 0; r < 4; ++r) {
            int o = obase + r;
            if (o < M) {
                float bb = ds[0] * bias[0 * M + o] + ds[1] * bias[1 * M + o]
                         + ds[2] * bias[2 * M + o] + ds[3] * bias[3 * M + o];
                dst[o] = bl[r] + bb;
            }
        }
    }
}

extern "C" void kernel_launch(void* const* d_in, const int* in_sizes, int n_in,
                              void* d_out, int out_size, void* d_ws, size_t ws_size,
                              hipStream_t stream) {
    const float* x  = (const float*)d_in[0];
    const float* W0 = (const float*)d_in[1];
    const float* b0 = (const float*)d_in[2];
    const float* W1 = (const float*)d_in[3];
    const float* b1 = (const float*)d_in[4];
    const float* W2 = (const float*)d_in[5];
    const float* b2 = (const float*)d_in[6];
    float* out = (float*)d_out;

    char* p = (char*)d_ws;
    auto alloc = [&](size_t bytes) { char* r = p; p += (bytes + 255) & ~(size_t)255; return r; };

    float* dcoef = (float*)alloc(BATCH * 4 * sizeof(float));
    u16* whi0 = (u16*)alloc((size_t)4 * HID * KP0 * 2);
    u16* wlo0 = (u16*)alloc((size_t)4 * HID * KP0 * 2);
    u16* whi1 = (u16*)alloc((size_t)4 * HID * HID * 2);
    u16* wlo1 = (u16*)alloc((size_t)4 * HID * HID * 2);
    u16* whi2 = (u16*)alloc((size_t)4 * MP2 * HID * 2);
    u16* wlo2 = (u16*)alloc((size_t)4 * MP2 * HID * 2);
    u16* h0hi = (u16*)alloc((size_t)BATCH * KP0 * 2);
    u16* h0lo = (u16*)alloc((size_t)BATCH * KP0 * 2);
    u16* hahi = (u16*)alloc((size_t)BATCH * HID * 2);
    u16* halo = (u16*)alloc((size_t)BATCH * HID * 2);
    u16* hbhi = (u16*)alloc((size_t)BATCH * HID * 2);
    u16* hblo = (u16*)alloc((size_t)BATCH * HID * 2);

    prep_all<<<dim3((PREP_TOT + 255) / 256), 256, 0, stream>>>(
        x, W0, W1, W2, whi0, wlo0, whi1, wlo1, whi2, wlo2, h0hi, h0lo, dcoef);

    // layer 0: K=352pad, M=512
    layer_fused<KP0, KP0 + 8, 0><<<dim3(BATCH / 16, HID / 64), 256, 0, stream>>>(
        whi0, wlo0, h0hi, h0lo, b0, dcoef, HID, HID, hahi, halo, nullptr);

    // layer 1: K=512, M=512
    layer_fused<HID, HID + 8, 0><<<dim3(BATCH / 16, HID / 64), 256, 0, stream>>>(
        whi1, wlo1, hahi, halo, b1, dcoef, HID, HID, hbhi, hblo, nullptr);

    // layer 2: K=512, M=311 (Mp=320)
    layer_fused<HID, HID + 8, 1><<<dim3(BATCH / 16, MP2 / 64), 256, 0, stream>>>(
        whi2, wlo2, hbhi, hblo, b2, dcoef, MP2, OUTD, nullptr, nullptr, out);
}

// Round 5
// 102.178 us; speedup vs baseline: 1.2628x; 1.2628x over previous
//
#include <hip/hip_runtime.h>
#include <math.h>

#define NSLICES 4
#define HID 512
#define IN_FEAT 342
#define OUTD 311
#define BATCH 256
#define KP0 352           // layer-0 padded K (11 chunks of 32)
#define MP2 320           // layer-2 padded M
#define XROW (IN_FEAT + 1)

typedef unsigned short u16;
typedef short bf16x8 __attribute__((ext_vector_type(8)));
typedef float f32x4 __attribute__((ext_vector_type(4)));

__device__ __forceinline__ u16 f2bf_rne(float v) {
    unsigned int x = __float_as_uint(v);
    unsigned int r = (x + 0x7fffu + ((x >> 16) & 1u)) >> 16;
    return (u16)r;
}
__device__ __forceinline__ float bf2f(u16 u) {
    return __uint_as_float(((unsigned int)u) << 16);
}

// ================= combined prep (unchanged from R4) =================
#define C0 (4 * 512 * 44)
#define C1 (4 * 512 * 64)
#define C2 (4 * 320 * 64)
#define CX (256 * 44)
#define PREP_TOT (C0 + C1 + C2 + CX + 256)

union U8 { u16 u[8]; uint4 v; };

__global__ __launch_bounds__(256) void prep_all(
    const float* __restrict__ x,
    const float* __restrict__ W0, const float* __restrict__ W1, const float* __restrict__ W2,
    u16* __restrict__ whi0, u16* __restrict__ wlo0,
    u16* __restrict__ whi1, u16* __restrict__ wlo1,
    u16* __restrict__ whi2, u16* __restrict__ wlo2,
    u16* __restrict__ h0hi, u16* __restrict__ h0lo,
    float* __restrict__ dcoef)
{
    int i = blockIdx.x * 256 + threadIdx.x;
    if (i >= PREP_TOT) return;

    if (i >= C0 + C1 + C2 + CX) {           // ---- dcoef ----
        int b = i - (C0 + C1 + C2 + CX);
        float ps = 4.f * x[(size_t)b * XROW + IN_FEAT];
        float fl = floorf(ps);
        float mu = ps - fl;
        int i1 = ((int)fl) & 3;
        float mu2 = mu * mu, mu3 = mu2 * mu;
        float c0 = -0.5f * mu3 + mu2 - 0.5f * mu;
        float c1 = 1.5f * mu3 - 2.5f * mu2 + 1.0f;
        float c2 = -1.5f * mu3 + 2.0f * mu2 + 0.5f * mu;
        float c3 = 0.5f * mu3 - 0.5f * mu2;
        float d[4];
        d[(i1 + 3) & 3] = c0;
        d[i1]           = c1;
        d[(i1 + 1) & 3] = c2;
        d[(i1 + 2) & 3] = c3;
        *reinterpret_cast<float4*>(dcoef + b * 4) = make_float4(d[0], d[1], d[2], d[3]);
        return;
    }

    float src[8];
    u16* dhi; u16* dlo; size_t doff;
    if (i < C0) {                            // ---- W0 ----
        int row = i / 44, c = i - row * 44;
        int k = c * 8;
#pragma unroll
        for (int j = 0; j < 8; j++) {
            int kk = k + j;
            src[j] = (kk < IN_FEAT) ? W0[(size_t)row * IN_FEAT + kk] : 0.f;
        }
        dhi = whi0; dlo = wlo0; doff = (size_t)row * KP0 + k;
    } else if (i < C0 + C1) {                // ---- W1 ----
        int l = i - C0;
        int row = l >> 6, c = l & 63;
        int k = c * 8;
        const float* p = W1 + (size_t)row * HID + k;
#pragma unroll
        for (int j = 0; j < 8; j++) src[j] = p[j];
        dhi = whi1; dlo = wlo1; doff = (size_t)row * HID + k;
    } else if (i < C0 + C1 + C2) {           // ---- W2 (M padded to 320) ----
        int l = i - C0 - C1;
        int row = l >> 6, c = l & 63;
        int k = c * 8;
        int s = row / 320, o = row - s * 320;
        if (o < OUTD) {
            const float* p = W2 + ((size_t)s * OUTD + o) * HID + k;
#pragma unroll
            for (int j = 0; j < 8; j++) src[j] = p[j];
        } else {
#pragma unroll
            for (int j = 0; j < 8; j++) src[j] = 0.f;
        }
        dhi = whi2; dlo = wlo2; doff = (size_t)row * HID + k;
    } else {                                 // ---- x -> H0 ----
        int l = i - C0 - C1 - C2;
        int b = l / 44, c = l - b * 44;
        int k = c * 8;
#pragma unroll
        for (int j = 0; j < 8; j++) {
            int kk = k + j;
            src[j] = (kk < IN_FEAT) ? x[(size_t)b * XROW + kk] : 0.f;
        }
        dhi = h0hi; dlo = h0lo; doff = (size_t)b * KP0 + k;
    }

    U8 hi, lo;
#pragma unroll
    for (int j = 0; j < 8; j++) {
        u16 h = f2bf_rne(src[j]);
        hi.u[j] = h;
        lo.u[j] = f2bf_rne(src[j] - bf2f(h));
    }
    *reinterpret_cast<uint4*>(dhi + doff) = hi.v;
    *reinterpret_cast<uint4*>(dlo + doff) = lo.v;
}

// ================= fused layer v2: wave = slice, 16x16 tile, LDS blend =================
// out[b][o] = act( sum_s d_s(b) * ( sum_k W[s][o][k]*H[b][k] + bias[s][o] ) )
// grid (BATCH/16, Mp/16); block 256 = 4 waves, wave s computes slice s.
// H tile (16 rows x KP, hi+lo) in LDS (row stride KLDS odd-in-16B -> conflict-free).
// Blend: wave s writes d_s*(sum+bias_s) to sAcc[s], barrier, 256 thr reduce+act+store.
template<int KP, int KLDS, int FINAL>
__global__ __launch_bounds__(256, 2) void layer_fused2(
    const u16* __restrict__ Whi, const u16* __restrict__ Wlo,
    const u16* __restrict__ Hhi, const u16* __restrict__ Hlo,
    const float* __restrict__ bias, const float* __restrict__ dcoef,
    int Mp, int M,
    u16* __restrict__ Ohi, u16* __restrict__ Olo, float* __restrict__ out)
{
    __shared__ __align__(16) u16 sHhi[16 * KLDS];
    __shared__ __align__(16) u16 sHlo[16 * KLDS];
    __shared__ float sAcc[4][16][17];

    const int tid = (int)threadIdx.x;
    const int b0 = blockIdx.x * 16;
    const int o0 = blockIdx.y * 16;

    constexpr int CH = KP / 8;
    for (int idx = tid; idx < 16 * CH; idx += 256) {
        int r = idx / CH, c = idx - r * CH;
        size_t g = (size_t)(b0 + r) * KP + c * 8;
        *reinterpret_cast<uint4*>(&sHhi[r * KLDS + c * 8]) =
            *reinterpret_cast<const uint4*>(Hhi + g);
        *reinterpret_cast<uint4*>(&sHlo[r * KLDS + c * 8]) =
            *reinterpret_cast<const uint4*>(Hlo + g);
    }
    __syncthreads();

    const int lane = tid & 63;
    const int s  = tid >> 6;          // wave -> slice
    const int m  = lane & 15;
    const int q  = lane >> 4;

    const u16* hp_hi = &sHhi[m * KLDS + q * 8];
    const u16* hp_lo = &sHlo[m * KLDS + q * 8];
    const size_t wrow = ((size_t)s * Mp + o0 + m) * KP + q * 8;
    const u16* wp_hi = Whi + wrow;
    const u16* wp_lo = Wlo + wrow;

    f32x4 a0 = {0.f, 0.f, 0.f, 0.f};
    f32x4 a1 = {0.f, 0.f, 0.f, 0.f};
    f32x4 a2 = {0.f, 0.f, 0.f, 0.f};
#pragma unroll
    for (int c = 0; c < KP / 32; ++c) {
        bf16x8 ah = *reinterpret_cast<const bf16x8*>(wp_hi + c * 32);
        bf16x8 al = *reinterpret_cast<const bf16x8*>(wp_lo + c * 32);
        bf16x8 bh = *reinterpret_cast<const bf16x8*>(hp_hi + c * 32);
        bf16x8 b_l = *reinterpret_cast<const bf16x8*>(hp_lo + c * 32);
        a0 = __builtin_amdgcn_mfma_f32_16x16x32_bf16(ah, bh, a0, 0, 0, 0);
        a1 = __builtin_amdgcn_mfma_f32_16x16x32_bf16(ah, b_l, a1, 0, 0, 0);
        a2 = __builtin_amdgcn_mfma_f32_16x16x32_bf16(al, bh, a2, 0, 0, 0);
    }
    f32x4 sum = a0 + a1 + a2;

    // wave-phase blend: scale by d_s(b) and fold this slice's bias
    const float ds = dcoef[(size_t)(b0 + m) * 4 + s];
#pragma unroll
    for (int r = 0; r < 4; ++r) {
        int o = o0 + q * 4 + r;
        float bb = (o < M) ? bias[(size_t)s * M + o] : 0.f;
        sAcc[s][q * 4 + r][m] = ds * (sum[r] + bb);
    }
    __syncthreads();

    // reduce 4 slices, activate, store. tid -> (o_l = tid&15, b_l = tid>>4)
    const int o_l = tid & 15;
    const int b_l = tid >> 4;
    float v = sAcc[0][o_l][b_l] + sAcc[1][o_l][b_l]
            + sAcc[2][o_l][b_l] + sAcc[3][o_l][b_l];
    const int o = o0 + o_l;
    const int b = b0 + b_l;
    if (!FINAL) {
        float e = (v > 0.f) ? v : expm1f(v);
        u16 h = f2bf_rne(e);
        Ohi[(size_t)b * M + o] = h;
        Olo[(size_t)b * M + o] = f2bf_rne(e - bf2f(h));
    } else {
        if (o < M) out[(size_t)b * M + o] = v;
    }
}

extern "C" void kernel_launch(void* const* d_in, const int* in_sizes, int n_in,
                              void* d_out, int out_size, void* d_ws, size_t ws_size,
                              hipStream_t stream) {
    const float* x  = (const float*)d_in[0];
    const float* W0 = (const float*)d_in[1];
    const float* b0 = (const float*)d_in[2];
    const float* W1 = (const float*)d_in[3];
    const float* b1 = (const float*)d_in[4];
    const float* W2 = (const float*)d_in[5];
    const float* b2 = (const float*)d_in[6];
    float* out = (float*)d_out;

    char* p = (char*)d_ws;
    auto alloc = [&](size_t bytes) { char* r = p; p += (bytes + 255) & ~(size_t)255; return r; };

    float* dcoef = (float*)alloc(BATCH * 4 * sizeof(float));
    u16* whi0 = (u16*)alloc((size_t)4 * HID * KP0 * 2);
    u16* wlo0 = (u16*)alloc((size_t)4 * HID * KP0 * 2);
    u16* whi1 = (u16*)alloc((size_t)4 * HID * HID * 2);
    u16* wlo1 = (u16*)alloc((size_t)4 * HID * HID * 2);
    u16* whi2 = (u16*)alloc((size_t)4 * MP2 * HID * 2);
    u16* wlo2 = (u16*)alloc((size_t)4 * MP2 * HID * 2);
    u16* h0hi = (u16*)alloc((size_t)BATCH * KP0 * 2);
    u16* h0lo = (u16*)alloc((size_t)BATCH * KP0 * 2);
    u16* hahi = (u16*)alloc((size_t)BATCH * HID * 2);
    u16* halo = (u16*)alloc((size_t)BATCH * HID * 2);
    u16* hbhi = (u16*)alloc((size_t)BATCH * HID * 2);
    u16* hblo = (u16*)alloc((size_t)BATCH * HID * 2);

    prep_all<<<dim3((PREP_TOT + 255) / 256), 256, 0, stream>>>(
        x, W0, W1, W2, whi0, wlo0, whi1, wlo1, whi2, wlo2, h0hi, h0lo, dcoef);

    // layer 0: K=352pad, M=512 -> grid (16, 32)
    layer_fused2<KP0, KP0 + 8, 0><<<dim3(BATCH / 16, HID / 16), 256, 0, stream>>>(
        whi0, wlo0, h0hi, h0lo, b0, dcoef, HID, HID, hahi, halo, nullptr);

    // layer 1: K=512, M=512 -> grid (16, 32)
    layer_fused2<HID, HID + 8, 0><<<dim3(BATCH / 16, HID / 16), 256, 0, stream>>>(
        whi1, wlo1, hahi, halo, b1, dcoef, HID, HID, hbhi, hblo, nullptr);

    // layer 2: K=512, M=311 (Mp=320) -> grid (16, 20)
    layer_fused2<HID, HID + 8, 1><<<dim3(BATCH / 16, MP2 / 16), 256, 0, stream>>>(
        whi2, wlo2, hbhi, hblo, b2, dcoef, MP2, OUTD, nullptr, nullptr, out);
}